// Round 3
// baseline (620.982 us; speedup 1.0000x reference)
//
#include <hip/hip_runtime.h>

#define F 3
#define V 512
#define D 8192
#define B 64
#define ITERS 10

typedef __bf16 bf16_t;
typedef __bf16 bf16x8 __attribute__((ext_vector_type(8)));
typedef __bf16 bf16x4 __attribute__((ext_vector_type(4)));
typedef float f32x4 __attribute__((ext_vector_type(4)));

// ---------------------------------------------------------------------------
// init A (small): est0 = bf16(init_estimates), zero sims + flags
// ---------------------------------------------------------------------------
__global__ void k_init_small(const float* __restrict__ ie, bf16_t* __restrict__ est0,
                             float* __restrict__ simBase, int* __restrict__ anydiff) {
  long tid = (long)blockIdx.x * blockDim.x + threadIdx.x;
  long NT  = (long)gridDim.x * blockDim.x;
  for (long i = tid * 4; i < (long)B * F * D; i += NT * 4) {
    f32x4 x = *(const f32x4*)(ie + i);
    bf16x4 y;
    y[0] = (bf16_t)x[0]; y[1] = (bf16_t)x[1]; y[2] = (bf16_t)x[2]; y[3] = (bf16_t)x[3];
    *(bf16x4*)(est0 + i) = y;
  }
  f32x4 z = {0.f, 0.f, 0.f, 0.f};
  for (long i = tid * 4; i < (long)(ITERS + 1) * F * B * V; i += NT * 4)
    *(f32x4*)(simBase + i) = z;
  if (tid < 16) anydiff[tid] = 0;
}

// ---------------------------------------------------------------------------
// init B: single pass over codebooks -> Cb (bf16, [f][v][d]) and
// CbT (bf16, [f][d][v]) via LDS transpose. Reads the 100 MB fp32 once.
// grid (128 dt, 8 vt, 3 f) x 256 threads, 64x64 tiles.
// ---------------------------------------------------------------------------
__global__ __launch_bounds__(256) void k_init_cb(const float* __restrict__ Csrc,
                                                 bf16_t* __restrict__ Cb,
                                                 bf16_t* __restrict__ CbT) {
  int f = blockIdx.z, vt = blockIdx.y, dt = blockIdx.x;
  __shared__ bf16_t tile[64 * 65];
  int t = threadIdx.x;
  int v0 = vt * 64, d0 = dt * 64;
#pragma unroll
  for (int p = 0; p < 16; ++p) {
    int q = t + 256 * p;
    int i = q >> 6, j = q & 63;  // lanes cover j contiguously -> coalesced
    bf16_t x = (bf16_t)Csrc[((long)(f * V + v0 + i)) * D + d0 + j];
    tile[i * 65 + j] = x;
    Cb[((long)(f * V + v0 + i)) * D + d0 + j] = x;
  }
  __syncthreads();
#pragma unroll
  for (int p = 0; p < 16; ++p) {
    int q = t + 256 * p;
    int jj = q >> 6, ii = q & 63;
    CbT[((long)f * D + d0 + jj) * V + v0 + ii] = tile[ii * 65 + jj];
  }
}

// ---------------------------------------------------------------------------
// kernel A: sim[f][b][v] += sum_d A[b,f,d] * Cb[f][v][d]
//   iter < ITERS : A = inputs * est_f1 * est_f2 ; iter == ITERS: A = est
// grid (16 ksplit, 8 vtiles, 3 f) = 384 blocks x 256 threads.
// B-frags loaded DIRECTLY from global (zero in-block reuse); only A in LDS.
// Exact integer arithmetic throughout (values in {-1,0,1}, sums < 2^24).
// ---------------------------------------------------------------------------
__global__ __launch_bounds__(256) void k_sim(const float* __restrict__ inputs,
                                             const bf16_t* __restrict__ Cb,
                                             const bf16_t* __restrict__ est0,
                                             const bf16_t* __restrict__ est1,
                                             float* __restrict__ simBase,
                                             const int* __restrict__ anydiff, int iter) {
  const int f = blockIdx.z, vt = blockIdx.y, ks = blockIdx.x;
  const bf16_t* est;
  float* sim;
  const bool is_final = (iter >= ITERS);
  if (is_final) {
    int first0 = ITERS;
    for (int i = 0; i < ITERS; ++i)
      if (anydiff[i] == 0) { first0 = i; break; }
    int par = (first0 < ITERS) ? ((first0 + 1) & 1) : 0;
    est = par ? est1 : est0;
    sim = simBase + (long)ITERS * (F * B * V);
  } else {
    for (int i = 0; i < iter; ++i)
      if (anydiff[i] == 0) return;  // converged: uniform exit
    est = (iter & 1) ? est1 : est0;
    sim = simBase + (long)iter * (F * B * V);
  }
  const int f1 = (f + 1) % 3, f2 = (f + 2) % 3;

  __shared__ __attribute__((aligned(16))) bf16_t lA[64 * 136];  // 64 b x 128 d, pad 8

  const int t = threadIdx.x;
  const int lane = t & 63, w = t >> 6;
  const int lm = lane & 15, quad = lane >> 4;

  f32x4 zero = {0.f, 0.f, 0.f, 0.f};
  f32x4 acc[4];
#pragma unroll
  for (int mt = 0; mt < 4; ++mt) acc[mt] = zero;

  const int v0 = vt * 64;
  const int dbase = ks * 512;
  // B-frag row pointer: n = v0 + w*16 + lm, natural [v][d] layout
  const bf16_t* bp = Cb + ((long)(f * V + v0 + w * 16 + lm)) * D + dbase;

  for (int c = 0; c < 4; ++c) {
    const int d0c = dbase + c * 128;
    __syncthreads();
    // stage A: 64 b x 128 d
#pragma unroll
    for (int p = 0; p < 4; ++p) {
      int q = t + 256 * p;
      int b = q >> 4, dd = (q & 15) * 8;
      if (is_final) {
        *(bf16x8*)&lA[b * 136 + dd] =
            *(const bf16x8*)(est + ((long)b * F + f) * D + d0c + dd);
      } else {
        const float* ip = inputs + (long)b * D + d0c + dd;
        f32x4 x0 = *(const f32x4*)ip;
        f32x4 x1 = *(const f32x4*)(ip + 4);
        bf16x8 e1 = *(const bf16x8*)(est + ((long)b * F + f1) * D + d0c + dd);
        bf16x8 e2 = *(const bf16x8*)(est + ((long)b * F + f2) * D + d0c + dd);
        bf16x8 o;
#pragma unroll
        for (int i = 0; i < 4; ++i) {
          o[i]     = (bf16_t)(x0[i] * (float)e1[i]     * (float)e2[i]);
          o[i + 4] = (bf16_t)(x1[i] * (float)e1[i + 4] * (float)e2[i + 4]);
        }
        *(bf16x8*)&lA[b * 136 + dd] = o;
      }
    }
    __syncthreads();
#pragma unroll
    for (int ks2 = 0; ks2 < 4; ++ks2) {
      const int kb = ks2 * 32 + quad * 8;
      bf16x8 bfrag = *(const bf16x8*)(bp + c * 128 + kb);  // direct global
#pragma unroll
      for (int mt = 0; mt < 4; ++mt) {
        bf16x8 afrag = *(const bf16x8*)&lA[(mt * 16 + lm) * 136 + kb];
        acc[mt] = __builtin_amdgcn_mfma_f32_16x16x32_bf16(afrag, bfrag, acc[mt], 0, 0, 0);
      }
    }
  }
  const int v = v0 + w * 16 + lm;
#pragma unroll
  for (int mt = 0; mt < 4; ++mt)
#pragma unroll
    for (int r = 0; r < 4; ++r) {
      int b = mt * 16 + quad * 4 + r;
      atomicAdd(&sim[(f * B + b) * V + v], acc[mt][r]);
    }
}

// ---------------------------------------------------------------------------
// kernel B: est' = sign(sim . C), exact 256*h + l split + convergence flag.
// grid (128 dtiles of 64, 3 f) = 384 blocks x 256 threads. M=64 N=64 K=512.
// B-frags (CbT, [d][v]) loaded directly from global; A hi/lo planes in LDS.
// ---------------------------------------------------------------------------
__global__ __launch_bounds__(256) void k_upd(const float* __restrict__ simBase,
                                             const bf16_t* __restrict__ CbT,
                                             bf16_t* __restrict__ est0,
                                             bf16_t* __restrict__ est1,
                                             int* __restrict__ anydiff, int iter) {
  const int f = blockIdx.y;
  const int d0 = blockIdx.x * 64;
  for (int i = 0; i < iter; ++i)
    if (anydiff[i] == 0) return;
  const bf16_t* estIn = (iter & 1) ? est1 : est0;
  bf16_t* estOut = (iter & 1) ? est0 : est1;
  const float* sim = simBase + (long)iter * (F * B * V) + f * (B * V);

  __shared__ __attribute__((aligned(16))) bf16_t lAh[64 * 136];  // 64 b x 128 v
  __shared__ __attribute__((aligned(16))) bf16_t lAl[64 * 136];

  const int t = threadIdx.x;
  const int lane = t & 63, w = t >> 6;
  const int lm = lane & 15, quad = lane >> 4;

  f32x4 zero = {0.f, 0.f, 0.f, 0.f};
  f32x4 accH[4], accL[4];
#pragma unroll
  for (int mt = 0; mt < 4; ++mt) { accH[mt] = zero; accL[mt] = zero; }

  // B-frag row pointer: n = d0 + w*16 + lm, natural [d][v] layout
  const bf16_t* bp = CbT + ((long)f * D + d0 + w * 16 + lm) * V;

  for (int c = 0; c < 4; ++c) {
    const int vb = c * 128;
    __syncthreads();
#pragma unroll
    for (int p = 0; p < 4; ++p) {
      int q = t + 256 * p;
      int b = q >> 4, vv = (q & 15) * 8;
      const float* sp = sim + b * V + vb + vv;
      bf16x8 h, l;
#pragma unroll
      for (int i = 0; i < 8; ++i) {
        int si = (int)sp[i];
        h[i] = (bf16_t)(float)(si >> 8);   // floor division: si = 256*h + l
        l[i] = (bf16_t)(float)(si & 255);  // l in [0,255], bf16-exact
      }
      *(bf16x8*)&lAh[b * 136 + vv] = h;
      *(bf16x8*)&lAl[b * 136 + vv] = l;
    }
    __syncthreads();
#pragma unroll
    for (int ks2 = 0; ks2 < 4; ++ks2) {
      const int kb = ks2 * 32 + quad * 8;
      bf16x8 bfrag = *(const bf16x8*)(bp + vb + kb);  // direct global
#pragma unroll
      for (int mt = 0; mt < 4; ++mt) {
        bf16x8 ah = *(const bf16x8*)&lAh[(mt * 16 + lm) * 136 + kb];
        bf16x8 al = *(const bf16x8*)&lAl[(mt * 16 + lm) * 136 + kb];
        accH[mt] = __builtin_amdgcn_mfma_f32_16x16x32_bf16(ah, bfrag, accH[mt], 0, 0, 0);
        accL[mt] = __builtin_amdgcn_mfma_f32_16x16x32_bf16(al, bfrag, accL[mt], 0, 0, 0);
      }
    }
  }
  bool anyd = false;
  const int d = d0 + w * 16 + lm;
#pragma unroll
  for (int mt = 0; mt < 4; ++mt)
#pragma unroll
    for (int r = 0; r < 4; ++r) {
      int b = mt * 16 + quad * 4 + r;
      float val = 256.f * accH[mt][r] + accL[mt][r];
      float s = (val > 0.f) ? 1.f : ((val < 0.f) ? -1.f : 0.f);
      long idx = ((long)b * F + f) * D + d;
      estOut[idx] = (bf16_t)s;
      anyd |= ((float)estIn[idx] != s);
    }
  if (__any(anyd) && lane == 0) atomicOr(&anydiff[iter], 1);
}

// ---------------------------------------------------------------------------
// final: argmax over V per (b,f) (first-max tie-break) + iteration count
// ---------------------------------------------------------------------------
__global__ __launch_bounds__(64) void k_out(const float* __restrict__ simBase,
                                            const int* __restrict__ anydiff,
                                            int* __restrict__ out) {
  const float* sim = simBase + (long)ITERS * (F * B * V);
  int bid = blockIdx.x;
  int b = bid / F, f = bid % F;
  int lane = threadIdx.x;
  const float* row = sim + (f * B + b) * V;
  float best = -1e30f;
  int bidx = 0;
#pragma unroll
  for (int i = 0; i < V / 64; ++i) {
    int v = lane + 64 * i;
    float x = row[v];
    if (x > best) { best = x; bidx = v; }
  }
  for (int off = 32; off; off >>= 1) {
    float ov = __shfl_down(best, off, 64);
    int oi = __shfl_down(bidx, off, 64);
    if (ov > best || (ov == best && oi < bidx)) { best = ov; bidx = oi; }
  }
  if (lane == 0) out[b * F + f] = bidx;
  if (bid == 0 && lane == 0) {
    int first0 = ITERS;
    for (int i = 0; i < ITERS; ++i)
      if (anydiff[i] == 0) { first0 = i; break; }
    int cnt = (first0 < ITERS) ? (first0 + 1) : ITERS;
    out[B * F] = cnt - 1;
  }
}

// ---------------------------------------------------------------------------
extern "C" void kernel_launch(void* const* d_in, const int* in_sizes, int n_in,
                              void* d_out, int out_size, void* d_ws, size_t ws_size,
                              hipStream_t stream) {
  const float* inputs    = (const float*)d_in[0];  // (B, D)
  const float* init_est  = (const float*)d_in[1];  // (B, F, D)
  const float* codebooks = (const float*)d_in[2];  // (F, V, D)

  char* w = (char*)d_ws;
  size_t o = 0;
  auto alloc = [&](size_t bytes) -> void* {
    void* p = w + o;
    o = (o + bytes + 255) & ~(size_t)255;
    return p;
  };
  bf16_t* Cb   = (bf16_t*)alloc((size_t)F * V * D * 2);
  bf16_t* CbT  = (bf16_t*)alloc((size_t)F * D * V * 2);
  bf16_t* est0 = (bf16_t*)alloc((size_t)B * F * D * 2);
  bf16_t* est1 = (bf16_t*)alloc((size_t)B * F * D * 2);
  float* simBase = (float*)alloc((size_t)(ITERS + 1) * F * B * V * 4);
  int* anydiff = (int*)alloc(64);

  k_init_small<<<1024, 256, 0, stream>>>(init_est, est0, simBase, anydiff);
  k_init_cb<<<dim3(128, 8, 3), 256, 0, stream>>>(codebooks, Cb, CbT);

  for (int j = 0; j < ITERS; ++j) {
    k_sim<<<dim3(16, 8, 3), 256, 0, stream>>>(inputs, Cb, est0, est1, simBase, anydiff, j);
    k_upd<<<dim3(128, 3), 256, 0, stream>>>(simBase, CbT, est0, est1, anydiff, j);
  }
  k_sim<<<dim3(16, 8, 3), 256, 0, stream>>>(inputs, Cb, est0, est1, simBase, anydiff, ITERS);
  k_out<<<B * F, 64, 0, stream>>>(simBase, anydiff, (int*)d_out);
}